// Round 14
// baseline (170.088 us; speedup 1.0000x reference)
//
#include <hip/hip_runtime.h>
#include <hip/hip_bf16.h>
#include <stdint.h>

#define NB 8
#define CIN 256
#define IC 128
#define NP 4096   // 64*64 positions per batch

typedef __attribute__((ext_vector_type(8))) short s8v;    // 8 bf16 (4 VGPRs)
typedef __attribute__((ext_vector_type(4))) short s4v;    // 4 bf16
typedef __attribute__((ext_vector_type(16))) float f16v;  // 32x32 MFMA acc
typedef __attribute__((ext_vector_type(4))) float f4v;

#define MFMA32(a, b, c) __builtin_amdgcn_mfma_f32_32x32x16_bf16(a, b, c, 0, 0, 0)

__device__ __forceinline__ unsigned short f2bf(float f) {
  union { float f; unsigned int u; } v; v.f = f;
  unsigned int u = v.u;
  return (unsigned short)((u + 0x7FFFu + ((u >> 16) & 1u)) >> 16);
}

__device__ __forceinline__ unsigned short f2bf_h(float f) {
  __hip_bfloat16 h = __float2bfloat16(f);
  union { __hip_bfloat16 h; unsigned short u; } cv; cv.h = h;
  return cv.u;
}

__device__ __forceinline__ float bf2f(short s) {
  union { unsigned int u; float f; } cv;
  cv.u = ((unsigned int)(unsigned short)s) << 16;
  return cv.f;
}

typedef const unsigned int __attribute__((address_space(1))) gas_u32;
typedef unsigned int __attribute__((address_space(3))) las_u32;
__device__ __forceinline__ void gload_lds16(const void* g, void* l) {
  __builtin_amdgcn_global_load_lds((gas_u32*)g, (las_u32*)l, 16, 0, 0);
}

// ---------------------------------------------------------------------------
// Kernel 0: one-shot weight conversion f32 -> bf16 (theta pre-scaled log2e).
// wB layout: [thwB | phwB | gwB | WwB], each 32768 shorts.
// ---------------------------------------------------------------------------
__global__ __launch_bounds__(256) void k_wprep(const float* __restrict__ thw,
    const float* __restrict__ phw, const float* __restrict__ gw,
    const float* __restrict__ Ww, unsigned short* __restrict__ wB) {
  const int g = blockIdx.x >> 5;                       // 0..3
  const int base = (blockIdx.x & 31) * 1024 + threadIdx.x * 4;
  const float* src = (g == 0) ? thw : ((g == 1) ? phw : ((g == 2) ? gw : Ww));
  const float sc = (g == 0) ? 1.44269504f : 1.0f;
  const f4v v = *(const f4v*)(src + base);
  ushort4 u;
  u.x = f2bf(v[0] * sc); u.y = f2bf(v[1] * sc);
  u.z = f2bf(v[2] * sc); u.w = f2bf(v[3] * sc);
  *(ushort4*)(wB + g * 32768 + base) = u;
}

// ---------------------------------------------------------------------------
// Kernel 1: three 1x1 convs with FUSED f32->bf16 transpose staging.
// Weights pre-converted bf16 (theta already log2e-scaled). p-tile 64;
// grid 512, XCD-aligned batches.
// ---------------------------------------------------------------------------
__global__ __launch_bounds__(256) void k_conv3(const float* __restrict__ x,
    const unsigned short* __restrict__ wB,
    const float* __restrict__ thb, const float* __restrict__ phb,
    const float* __restrict__ gb,
    unsigned short* __restrict__ Qg, unsigned short* __restrict__ Kg,
    unsigned short* __restrict__ Vtg) {
  __shared__ unsigned short X[64 * 256];   // [p][c] bf16, chunk-swizzle 2*(p&15)
  __shared__ unsigned short T[64][72];     // transpose staging
  const int t = threadIdx.x, lane = t & 63, wid = t >> 6;
  const int b = blockIdx.x & 7;            // XCD-aligned batch
  const int p0 = (blockIdx.x >> 3) * 64;
  const int hl = lane >> 5;
  const float* xb = x + (size_t)b * CIN * NP + p0;
  const int cl = t >> 4;          // 0..15
  const int p4 = (t & 15) * 4;    // 0..60
  for (int sub = 0; sub < 4; ++sub) {
    const int c0 = sub * 64;
#pragma unroll
    for (int j = 0; j < 4; ++j) {
      const int cloc = cl + j * 16;
      const f4v v = *(const f4v*)(xb + (size_t)(c0 + cloc) * NP + p4);
      ushort4 u;
      u.x = f2bf(v[0]); u.y = f2bf(v[1]); u.z = f2bf(v[2]); u.w = f2bf(v[3]);
      *(ushort4*)&T[cloc][p4 ^ ((cloc & 7) * 8)] = u;
    }
    __syncthreads();
    const int p = t >> 2;
#pragma unroll
    for (int half = 0; half < 2; ++half) {
      const int cg = (t & 3) + half * 4;   // 0..7
      alignas(16) unsigned short outv[8];
#pragma unroll
      for (int k = 0; k < 8; ++k)
        outv[k] = T[cg * 8 + k][p ^ (k * 8)];
      const int cc = sub * 8 + cg;         // global c-chunk 0..31
      *(uint4*)&X[p * 256 + 8 * (cc ^ (2 * (p & 15)))] = *(const uint4*)outv;
    }
    __syncthreads();
  }
  const int orow = wid * 32 + (lane & 31);

  for (int mat = 0; mat < 3; ++mat) {
    const unsigned short* WB = wB + mat * 32768;
    const float* Bs = (mat == 0) ? thb : ((mat == 1) ? phb : gb);
    const float wsc = (mat == 0) ? 1.44269504f : 1.0f;  // log2e on theta bias
    s8v wf[16];
#pragma unroll
    for (int s = 0; s < 16; ++s)
      wf[s] = *(const s8v*)&WB[(size_t)orow * CIN + hl * 8 + 16 * s];
    float br[16];
#pragma unroll
    for (int r = 0; r < 16; ++r)
      br[r] = Bs[wid * 32 + (r & 3) + 8 * (r >> 2) + 4 * hl] * wsc;

#pragma unroll
    for (int nt = 0; nt < 2; ++nt) {
      const int p = (lane & 31) + nt * 32;
      f16v acc;
#pragma unroll
      for (int i = 0; i < 16; ++i) acc[i] = 0.f;
#pragma unroll
      for (int s = 0; s < 16; ++s) {
        const int cc0 = hl + 2 * s;
        const s8v xf = *(const s8v*)&X[p * 256 + 8 * (cc0 ^ (2 * (p & 15)))];
        acc = MFMA32(wf[s], xf, acc);
      }
      if (mat < 2) {
        unsigned short* G = ((mat == 0) ? Qg : Kg) + ((size_t)b * NP + p0 + p) * IC;
#pragma unroll
        for (int grp = 0; grp < 4; ++grp) {
          const int d0 = wid * 32 + 8 * grp + 4 * hl;
          ushort4 u;
          u.x = f2bf(acc[grp * 4 + 0] + br[grp * 4 + 0]);
          u.y = f2bf(acc[grp * 4 + 1] + br[grp * 4 + 1]);
          u.z = f2bf(acc[grp * 4 + 2] + br[grp * 4 + 2]);
          u.w = f2bf(acc[grp * 4 + 3] + br[grp * 4 + 3]);
          *(ushort4*)(G + d0) = u;
        }
      } else {
        unsigned short* G = Vtg + (size_t)b * IC * NP + p0 + p;
#pragma unroll
        for (int r = 0; r < 16; ++r) {
          const int row = wid * 32 + (r & 3) + 8 * (r >> 2) + 4 * hl;
          G[(size_t)row * NP] = f2bf(acc[r] + br[r]);
        }
      }
    }
  }
}

// ---------------------------------------------------------------------------
// Kernel 2: flash attention, KV-split x3 (grid 768 = 3 blocks/CU — R13 had
// the resources for 3 waves/SIMD but only a 2-blocks/CU grid), KVBLK=32,
// launch_bounds(256,3). LDS 33.8 KB/block; K DMA-staged (chunk-swizzled),
// V reg-staged into 34-short padded rows (conflict-free).
// Split tile ranges over 128 tiles: {0,43,86,128}.
// ---------------------------------------------------------------------------
__global__ __launch_bounds__(256, 3) void k_attn(const unsigned short* __restrict__ Qg,
    const unsigned short* __restrict__ Kg, const unsigned short* __restrict__ Vtg,
    unsigned short* __restrict__ Opart01, unsigned short* __restrict__ Opart2,
    float2* __restrict__ stats) {
  __shared__ unsigned short Klds[2][32 * 128];  // chunk-swizzled by (kv&15)
  __shared__ unsigned short Vlds[2][128 * 34];  // [d][kv], rows padded to 68B
  const int t = threadIdx.x, lane = t & 63, wid = t >> 6;
  const int bid = blockIdx.x;
  const int b = bid & 7;                 // XCD-aligned: one batch per XCD L2
  const int q0 = ((bid >> 3) & 31) * 128;
  const int split = bid >> 8;            // 0..2
  const int tstart = (split == 0) ? 0 : ((split == 1) ? 43 : 86);
  const int tend   = (split == 0) ? 43 : ((split == 1) ? 86 : 128);
  const int hl = lane >> 5;
  const int q = q0 + wid * 32 + (lane & 31);
  const unsigned short* Qp = Qg + (size_t)b * NP * IC + (size_t)q * IC;
  s8v qf[8];
#pragma unroll
  for (int s = 0; s < 8; ++s)
    qf[s] = *(const s8v*)(Qp + hl * 8 + 16 * s);
  f16v oa[4];
#pragma unroll
  for (int dt = 0; dt < 4; ++dt)
#pragma unroll
    for (int i = 0; i < 16; ++i) oa[dt][i] = 0.f;
  float m = -3.0e38f, lsum = 0.f;
  const unsigned short* Kb = Kg + (size_t)b * NP * IC;
  const unsigned short* Vb = Vtg + (size_t)b * IC * NP;
  // V staging: thread t covers rows d = (t>>2)+64j (j=0,1), chunk c = t&3
  const int vd = t >> 2, vc = t & 3;

  uint4 vreg[2];
  // ---- prologue: stage tile tstart into buffer 0 ----
#pragma unroll
  for (int r = 0; r < 2; ++r) {
    const int ci = wid * 128 + r * 64 + lane;
    const int kv = ci >> 4, cc = ci & 15;
    gload_lds16(Kb + (size_t)(tstart * 32 + kv) * IC + 8 * (cc ^ (kv & 15)),
                (char*)&Klds[0][0] + wid * 2048 + r * 1024);
  }
  {
    const unsigned short* vs = Vb + tstart * 32 + vc * 8;
    vreg[0] = *(const uint4*)(vs + (size_t)vd * NP);
    vreg[1] = *(const uint4*)(vs + (size_t)(vd + 64) * NP);
    *(uint4*)&Vlds[0][vd * 34 + vc * 8] = vreg[0];
    *(uint4*)&Vlds[0][(vd + 64) * 34 + vc * 8] = vreg[1];
  }
  __syncthreads();

  for (int i = tstart; i < tend; ++i) {
    const int cur = (i - tstart) & 1;
    const bool more = (i < tend - 1);
    // ---- issue next-tile staging first (overlaps with compute below) ----
    if (more) {
      const int kv0n = (i + 1) * 32;
      const unsigned short* vs = Vb + kv0n + vc * 8;
      vreg[0] = *(const uint4*)(vs + (size_t)vd * NP);
      vreg[1] = *(const uint4*)(vs + (size_t)(vd + 64) * NP);
#pragma unroll
      for (int r = 0; r < 2; ++r) {
        const int ci = wid * 128 + r * 64 + lane;
        const int kv = ci >> 4, cc = ci & 15;
        gload_lds16(Kb + (size_t)(kv0n + kv) * IC + 8 * (cc ^ (kv & 15)),
                    (char*)&Klds[cur ^ 1][0] + wid * 2048 + r * 1024);
      }
    }
    // ---- S^T[k][q] = K * Q^T (log2e pre-scaled), 2-way split chains ----
    f16v sa, sb;
#pragma unroll
    for (int ii = 0; ii < 16; ++ii) { sa[ii] = 0.f; sb[ii] = 0.f; }
    const int kva = lane & 31;
    __builtin_amdgcn_s_setprio(1);
#pragma unroll
    for (int s = 0; s < 8; s += 2) {
      const int cc0 = hl + 2 * s;
      const s8v ka0 = *(const s8v*)&Klds[cur][kva * 128 + 8 * (cc0 ^ (kva & 15))];
      const s8v ka1 = *(const s8v*)&Klds[cur][kva * 128 + 8 * ((cc0 + 2) ^ (kva & 15))];
      sa = MFMA32(ka0, qf[s], sa);
      sb = MFMA32(ka1, qf[s + 1], sb);
    }
    __builtin_amdgcn_s_setprio(0);
    f16v st = sa + sb;
    // ---- online softmax (exp2 domain, defer-rescale THR=8, tree reduce) ----
    float tm[8];
#pragma unroll
    for (int ii = 0; ii < 8; ++ii) tm[ii] = fmaxf(st[ii], st[ii + 8]);
#pragma unroll
    for (int w = 4; w >= 1; w >>= 1)
#pragma unroll
      for (int ii = 0; ii < 8; ++ii) if (ii < w) tm[ii] = fmaxf(tm[ii], tm[ii + w]);
    const float pmax = fmaxf(tm[0], __shfl_xor(tm[0], 32));
    if (__any(pmax > m + 8.f)) {
      const float mn = fmaxf(m, pmax);
      const float sc = __builtin_amdgcn_exp2f(m - mn);
      m = mn;
      lsum *= sc;
#pragma unroll
      for (int dt = 0; dt < 4; ++dt)
#pragma unroll
        for (int ii = 0; ii < 16; ++ii) oa[dt][ii] *= sc;
    }
#pragma unroll
    for (int ii = 0; ii < 16; ++ii) st[ii] = __builtin_amdgcn_exp2f(st[ii] - m);
    float ts[8];
#pragma unroll
    for (int ii = 0; ii < 8; ++ii) ts[ii] = st[ii] + st[ii + 8];
#pragma unroll
    for (int w = 4; w >= 1; w >>= 1)
#pragma unroll
      for (int ii = 0; ii < 8; ++ii) if (ii < w) ts[ii] += ts[ii + w];
    lsum += ts[0] + __shfl_xor(ts[0], 32);
    s8v pf0, pf1;
#pragma unroll
    for (int ii = 0; ii < 8; ++ii) {
      pf0[ii] = (short)f2bf_h(st[ii]);
      pf1[ii] = (short)f2bf_h(st[8 + ii]);
    }
    // ---- write prefetched V into the other buffer (frees vreg pre-PV) ----
    if (more) {
      *(uint4*)&Vlds[cur ^ 1][vd * 34 + vc * 8] = vreg[0];
      *(uint4*)&Vlds[cur ^ 1][(vd + 64) * 34 + vc * 8] = vreg[1];
    }
    // ---- O^T[d][q] += V^T[d][k] * P^T[k][q], matched k-permutation ----
    __builtin_amdgcn_s_setprio(1);
#pragma unroll
    for (int ks = 0; ks < 2; ++ks) {
      const s8v pcur = (ks == 0) ? pf0 : pf1;
      const int k0 = 16 * ks + 4 * hl;
#pragma unroll
      for (int dt = 0; dt < 4; ++dt) {
        const int d = dt * 32 + (lane & 31);
        const s4v va  = *(const s4v*)&Vlds[cur][d * 34 + k0];
        const s4v vb2 = *(const s4v*)&Vlds[cur][d * 34 + k0 + 8];
        s8v vf;
        vf[0] = va[0]; vf[1] = va[1]; vf[2] = va[2]; vf[3] = va[3];
        vf[4] = vb2[0]; vf[5] = vb2[1]; vf[6] = vb2[2]; vf[7] = vb2[3];
        oa[dt] = MFMA32(vf, pcur, oa[dt]);
      }
    }
    __builtin_amdgcn_s_setprio(0);
    // one barrier per iter: drains K-DMA + V ds_writes, closes reads of cur
    __syncthreads();
  }
  // epilogue: normalized partial O + stats
  const float inv = 1.0f / lsum;
  unsigned short* Obase = (split == 2) ? Opart2
                        : Opart01 + (size_t)split * NB * NP * IC;
  unsigned short* Op = Obase + ((size_t)b * NP + q) * IC;
#pragma unroll
  for (int dt = 0; dt < 4; ++dt) {
#pragma unroll
    for (int grp = 0; grp < 4; ++grp) {
      const int d0 = dt * 32 + 8 * grp + 4 * hl;
      ushort4 u;
      u.x = f2bf_h(oa[dt][grp * 4 + 0] * inv);
      u.y = f2bf_h(oa[dt][grp * 4 + 1] * inv);
      u.z = f2bf_h(oa[dt][grp * 4 + 2] * inv);
      u.w = f2bf_h(oa[dt][grp * 4 + 3] * inv);
      *(ushort4*)(Op + d0) = u;
    }
  }
  if (hl == 0)
    stats[(size_t)split * NB * NP + (size_t)b * NP + q] = make_float2(m, lsum);
}

// ---------------------------------------------------------------------------
// Kernel 3: merge THREE partial O splits ONCE, then both output-channel
// halves' GEMM + residual. Grid 512 (8 batches x 64 p-tiles). Weights bf16.
// ---------------------------------------------------------------------------
__global__ __launch_bounds__(256) void k_out(const unsigned short* __restrict__ Opart01,
    const unsigned short* __restrict__ Opart2,
    const float2* __restrict__ stats,
    const unsigned short* __restrict__ WwB, const float* __restrict__ Wb,
    const float* __restrict__ x, float* __restrict__ out) {
  __shared__ unsigned short Y[64 * 128];  // [p][i], 16B-chunk swizzle by (p&15)
  const int t = threadIdx.x, lane = t & 63, wid = t >> 6;
  const int b = blockIdx.x & 7;           // XCD-aligned batch
  const int p0 = (blockIdx.x >> 3) * 64;
  const int hl = lane >> 5;
  // ---- merge-stage Y from the three partial splits (once) ----
  {
    const int p = t >> 2;
    const int quarter = t & 3;
    const int ihb = quarter * 32;
    const int gq = p0 + p;
    const float2 s0 = stats[(size_t)b * NP + gq];
    const float2 s1 = stats[(size_t)NB * NP + (size_t)b * NP + gq];
    const float2 s2 = stats[(size_t)2 * NB * NP + (size_t)b * NP + gq];
    const float mm = fmaxf(fmaxf(s0.x, s1.x), s2.x);
    const float w0 = s0.y * exp2f(s0.x - mm);
    const float w1 = s1.y * exp2f(s1.x - mm);
    const float w2 = s2.y * exp2f(s2.x - mm);
    const float rinv = 1.0f / (w0 + w1 + w2);
    const float a0 = w0 * rinv, a1 = w1 * rinv, a2 = w2 * rinv;
    const size_t rowoff = ((size_t)b * NP + gq) * IC + ihb;
    const unsigned short* P0 = Opart01 + rowoff;
    const unsigned short* P1 = Opart01 + (size_t)NB * NP * IC + rowoff;
    const unsigned short* P2 = Opart2 + rowoff;
#pragma unroll
    for (int c8 = 0; c8 < 4; ++c8) {
      const s8v v0 = *(const s8v*)(P0 + c8 * 8);
      const s8v v1 = *(const s8v*)(P1 + c8 * 8);
      const s8v v2 = *(const s8v*)(P2 + c8 * 8);
      alignas(16) unsigned short o[8];
#pragma unroll
      for (int j = 0; j < 8; ++j)
        o[j] = f2bf_h(a0 * bf2f(v0[j]) + a1 * bf2f(v1[j]) + a2 * bf2f(v2[j]));
      const int cc = quarter * 4 + c8;
      *(uint4*)&Y[p * 128 + 8 * (cc ^ (p & 15))] = *(const uint4*)o;
    }
  }
  __syncthreads();
  for (int mt = 0; mt < 2; ++mt) {
    const int orow = mt * 128 + wid * 32 + (lane & 31);
    s8v wf[8];
#pragma unroll
    for (int s = 0; s < 8; ++s)
      wf[s] = *(const s8v*)&WwB[(size_t)orow * IC + hl * 8 + 16 * s];
    float br[16];
#pragma unroll
    for (int r = 0; r < 16; ++r)
      br[r] = Wb[mt * 128 + wid * 32 + (r & 3) + 8 * (r >> 2) + 4 * hl];
#pragma unroll
    for (int nt = 0; nt < 2; ++nt) {
      const int p = (lane & 31) + nt * 32;
      f16v acc;
#pragma unroll
      for (int i = 0; i < 16; ++i) acc[i] = 0.f;
#pragma unroll
      for (int s = 0; s < 8; ++s) {
        const int cc0 = hl + 2 * s;
        const s8v yf = *(const s8v*)&Y[p * 128 + 8 * (cc0 ^ (p & 15))];
        acc = MFMA32(wf[s], yf, acc);
      }
      const size_t pidx = (size_t)b * CIN * NP + (size_t)(p0 + p);
#pragma unroll
      for (int r = 0; r < 16; ++r) {
        const int row = mt * 128 + wid * 32 + (r & 3) + 8 * (r >> 2) + 4 * hl;
        const size_t idx = pidx + (size_t)row * NP;
        out[idx] = acc[r] + br[r] + x[idx];
      }
    }
  }
}

// ---------------------------------------------------------------------------
extern "C" void kernel_launch(void* const* d_in, const int* in_sizes, int n_in,
                              void* d_out, int out_size, void* d_ws, size_t ws_size,
                              hipStream_t stream) {
  const float* x   = (const float*)d_in[0];
  const float* gw  = (const float*)d_in[1];
  const float* gb  = (const float*)d_in[2];
  const float* thw = (const float*)d_in[3];
  const float* thb = (const float*)d_in[4];
  const float* phw = (const float*)d_in[5];
  const float* phb = (const float*)d_in[6];
  const float* Ww  = (const float*)d_in[7];
  const float* Wb  = (const float*)d_in[8];
  float* out = (float*)d_out;

  // ws layout (ushorts): Opart01 8.39M | Q 4.19M | K 4.19M | Vt 4.19M |
  //                      stats 0.39M | wB 0.13M | Opart2 4.19M  (= 51.4MB)
  unsigned short* ws  = (unsigned short*)d_ws;
  unsigned short* Opart01 = ws;
  unsigned short* Qg  = ws + 8388608;
  unsigned short* Kg  = Qg + 4194304;
  unsigned short* Vtg = Kg + 4194304;
  float2* stats = (float2*)(Vtg + 4194304);
  unsigned short* wB = Vtg + 4194304 + 393216;
  unsigned short* Opart2 = wB + 131072;

  k_wprep<<<dim3(128), dim3(256), 0, stream>>>(thw, phw, gw, Ww, wB);
  k_conv3<<<dim3(512), dim3(256), 0, stream>>>(x, wB, thb, phb, gb,
                                               Qg, Kg, Vtg);
  k_attn<<<dim3(768), dim3(256), 0, stream>>>(Qg, Kg, Vtg, Opart01, Opart2, stats);
  k_out<<<dim3(512), dim3(256), 0, stream>>>(Opart01, Opart2, stats,
                                             wB + 98304, Wb, x, out);
}

// Round 15
// 141.455 us; speedup vs baseline: 1.2024x; 1.2024x over previous
//
#include <hip/hip_runtime.h>
#include <hip/hip_bf16.h>
#include <stdint.h>

#define NB 8
#define CIN 256
#define IC 128
#define NP 4096   // 64*64 positions per batch

typedef __attribute__((ext_vector_type(8))) short s8v;    // 8 bf16 (4 VGPRs)
typedef __attribute__((ext_vector_type(16))) float f16v;  // 32x32 MFMA acc
typedef __attribute__((ext_vector_type(4))) float f4v;

#define MFMA32(a, b, c) __builtin_amdgcn_mfma_f32_32x32x16_bf16(a, b, c, 0, 0, 0)

__device__ __forceinline__ unsigned short f2bf(float f) {
  union { float f; unsigned int u; } v; v.f = f;
  unsigned int u = v.u;
  return (unsigned short)((u + 0x7FFFu + ((u >> 16) & 1u)) >> 16);
}

__device__ __forceinline__ unsigned short f2bf_h(float f) {
  __hip_bfloat16 h = __float2bfloat16(f);
  union { __hip_bfloat16 h; unsigned short u; } cv; cv.h = h;
  return cv.u;
}

__device__ __forceinline__ float bf2f(short s) {
  union { unsigned int u; float f; } cv;
  cv.u = ((unsigned int)(unsigned short)s) << 16;
  return cv.f;
}

typedef const unsigned int __attribute__((address_space(1))) gas_u32;
typedef unsigned int __attribute__((address_space(3))) las_u32;
__device__ __forceinline__ void gload_lds16(const void* g, void* l) {
  __builtin_amdgcn_global_load_lds((gas_u32*)g, (las_u32*)l, 16, 0, 0);
}

// ---------------------------------------------------------------------------
// Kernel 0: one-shot weight conversion f32 -> bf16 (theta pre-scaled log2e).
// wB layout: [thwB | phwB | gwB | WwB], each 32768 shorts.
// ---------------------------------------------------------------------------
__global__ __launch_bounds__(256) void k_wprep(const float* __restrict__ thw,
    const float* __restrict__ phw, const float* __restrict__ gw,
    const float* __restrict__ Ww, unsigned short* __restrict__ wB) {
  const int g = blockIdx.x >> 5;                       // 0..3
  const int base = (blockIdx.x & 31) * 1024 + threadIdx.x * 4;
  const float* src = (g == 0) ? thw : ((g == 1) ? phw : ((g == 2) ? gw : Ww));
  const float sc = (g == 0) ? 1.44269504f : 1.0f;
  const f4v v = *(const f4v*)(src + base);
  ushort4 u;
  u.x = f2bf(v[0] * sc); u.y = f2bf(v[1] * sc);
  u.z = f2bf(v[2] * sc); u.w = f2bf(v[3] * sc);
  *(ushort4*)(wB + g * 32768 + base) = u;
}

// ---------------------------------------------------------------------------
// Kernel 1: three 1x1 convs with FUSED f32->bf16 transpose staging.
// Weights pre-converted bf16 (theta already log2e-scaled). p-tile 64;
// grid 512, XCD-aligned batches.
// ---------------------------------------------------------------------------
__global__ __launch_bounds__(256) void k_conv3(const float* __restrict__ x,
    const unsigned short* __restrict__ wB,
    const float* __restrict__ thb, const float* __restrict__ phb,
    const float* __restrict__ gb,
    unsigned short* __restrict__ Qg, unsigned short* __restrict__ Kg,
    unsigned short* __restrict__ Vtg) {
  __shared__ unsigned short X[64 * 256];   // [p][c] bf16, chunk-swizzle 2*(p&15)
  __shared__ unsigned short T[64][72];     // transpose staging
  const int t = threadIdx.x, lane = t & 63, wid = t >> 6;
  const int b = blockIdx.x & 7;            // XCD-aligned batch
  const int p0 = (blockIdx.x >> 3) * 64;
  const int hl = lane >> 5;
  const float* xb = x + (size_t)b * CIN * NP + p0;
  const int cl = t >> 4;          // 0..15
  const int p4 = (t & 15) * 4;    // 0..60
  for (int sub = 0; sub < 4; ++sub) {
    const int c0 = sub * 64;
#pragma unroll
    for (int j = 0; j < 4; ++j) {
      const int cloc = cl + j * 16;
      const f4v v = *(const f4v*)(xb + (size_t)(c0 + cloc) * NP + p4);
      ushort4 u;
      u.x = f2bf(v[0]); u.y = f2bf(v[1]); u.z = f2bf(v[2]); u.w = f2bf(v[3]);
      *(ushort4*)&T[cloc][p4 ^ ((cloc & 7) * 8)] = u;
    }
    __syncthreads();
    const int p = t >> 2;
#pragma unroll
    for (int half = 0; half < 2; ++half) {
      const int cg = (t & 3) + half * 4;   // 0..7
      alignas(16) unsigned short outv[8];
#pragma unroll
      for (int k = 0; k < 8; ++k)
        outv[k] = T[cg * 8 + k][p ^ (k * 8)];
      const int cc = sub * 8 + cg;         // global c-chunk 0..31
      *(uint4*)&X[p * 256 + 8 * (cc ^ (2 * (p & 15)))] = *(const uint4*)outv;
    }
    __syncthreads();
  }
  const int orow = wid * 32 + (lane & 31);

  for (int mat = 0; mat < 3; ++mat) {
    const unsigned short* WB = wB + mat * 32768;
    const float* Bs = (mat == 0) ? thb : ((mat == 1) ? phb : gb);
    const float wsc = (mat == 0) ? 1.44269504f : 1.0f;  // log2e on theta bias
    s8v wf[16];
#pragma unroll
    for (int s = 0; s < 16; ++s)
      wf[s] = *(const s8v*)&WB[(size_t)orow * CIN + hl * 8 + 16 * s];
    float br[16];
#pragma unroll
    for (int r = 0; r < 16; ++r)
      br[r] = Bs[wid * 32 + (r & 3) + 8 * (r >> 2) + 4 * hl] * wsc;

#pragma unroll
    for (int nt = 0; nt < 2; ++nt) {
      const int p = (lane & 31) + nt * 32;
      f16v acc;
#pragma unroll
      for (int i = 0; i < 16; ++i) acc[i] = 0.f;
#pragma unroll
      for (int s = 0; s < 16; ++s) {
        const int cc0 = hl + 2 * s;
        const s8v xf = *(const s8v*)&X[p * 256 + 8 * (cc0 ^ (2 * (p & 15)))];
        acc = MFMA32(wf[s], xf, acc);
      }
      if (mat < 2) {
        unsigned short* G = ((mat == 0) ? Qg : Kg) + ((size_t)b * NP + p0 + p) * IC;
#pragma unroll
        for (int grp = 0; grp < 4; ++grp) {
          const int d0 = wid * 32 + 8 * grp + 4 * hl;
          ushort4 u;
          u.x = f2bf(acc[grp * 4 + 0] + br[grp * 4 + 0]);
          u.y = f2bf(acc[grp * 4 + 1] + br[grp * 4 + 1]);
          u.z = f2bf(acc[grp * 4 + 2] + br[grp * 4 + 2]);
          u.w = f2bf(acc[grp * 4 + 3] + br[grp * 4 + 3]);
          *(ushort4*)(G + d0) = u;
        }
      } else {
        unsigned short* G = Vtg + (size_t)b * IC * NP + p0 + p;
#pragma unroll
        for (int r = 0; r < 16; ++r) {
          const int row = wid * 32 + (r & 3) + 8 * (r >> 2) + 4 * hl;
          G[(size_t)row * NP] = f2bf(acc[r] + br[r]);
        }
      }
    }
  }
}

// ---------------------------------------------------------------------------
// Kernel 2: flash attention, KV-split x2, launch_bounds(256,2).
// QK^T accumulators split 4-way. V in LDS: permuted-k contiguous fragments,
// stride 72 shorts, 16B-chunk index XOR'd by (d>>3)&7. Empirical-best attn
// config (R10: 93.2 us); conflicts counted but proven off-critical-path.
// ---------------------------------------------------------------------------
__global__ __launch_bounds__(256, 2) void k_attn(const unsigned short* __restrict__ Qg,
    const unsigned short* __restrict__ Kg, const unsigned short* __restrict__ Vtg,
    unsigned short* __restrict__ Opart, float2* __restrict__ stats) {
  __shared__ unsigned short Klds[2][64 * 128];  // chunk-swizzled by (kv&15)
  __shared__ unsigned short Vlds[2][128 * 72];  // [d][j perm], chunk-XOR (d>>3)&7
  const int t = threadIdx.x, lane = t & 63, wid = t >> 6;
  const int bid = blockIdx.x;
  const int b = bid & 7;                 // XCD-aligned: one batch per XCD L2
  const int q0 = ((bid >> 3) & 31) * 128;
  const int half = bid >> 8;             // KV half
  const int it0 = half * 32;
  const int hl = lane >> 5;
  const int q = q0 + wid * 32 + (lane & 31);
  const unsigned short* Qp = Qg + (size_t)b * NP * IC + (size_t)q * IC;
  s8v qf[8];
#pragma unroll
  for (int s = 0; s < 8; ++s)
    qf[s] = *(const s8v*)(Qp + hl * 8 + 16 * s);
  f16v oa[4];
#pragma unroll
  for (int dt = 0; dt < 4; ++dt)
#pragma unroll
    for (int i = 0; i < 16; ++i) oa[dt][i] = 0.f;
  float m = -3.0e38f, lsum = 0.f;
  const unsigned short* Kb = Kg + (size_t)b * NP * IC;
  const unsigned short* Vb = Vtg + (size_t)b * IC * NP;
  const int ch = t & 7, dbase = t >> 3;
  // V write offsets: chunk c1=2*(ch>>1) (+1 for hi half), within-chunk 4*(ch&1)
  const int c1 = 2 * (ch >> 1);
  const int w1 = 4 * (ch & 1);

  uint4 vreg[4];
  // ---- prologue: stage tile it0 into buffer 0 ----
#pragma unroll
  for (int r = 0; r < 4; ++r) {
    const int ci = wid * 256 + r * 64 + lane;
    const int kv = ci >> 4, cc = ci & 15;
    gload_lds16(Kb + (size_t)(it0 * 64 + kv) * IC + 8 * (cc ^ (kv & 15)),
                (char*)&Klds[0][0] + wid * 4096 + r * 1024);
  }
  {
    const unsigned short* vs = Vb + it0 * 64 + ch * 8;
#pragma unroll
    for (int j = 0; j < 4; ++j)
      vreg[j] = *(const uint4*)(vs + (size_t)(dbase + j * 32) * NP);
#pragma unroll
    for (int j = 0; j < 4; ++j) {
      const int d = dbase + j * 32;
      const int jd = (d >> 3) & 7;
      *(uint2*)&Vlds[0][d * 72 + 8 * (c1 ^ jd) + w1] = make_uint2(vreg[j].x, vreg[j].y);
      *(uint2*)&Vlds[0][d * 72 + 8 * ((c1 + 1) ^ jd) + w1] = make_uint2(vreg[j].z, vreg[j].w);
    }
  }
  __syncthreads();

  for (int it = it0; it < it0 + 32; ++it) {
    const int cur = it & 1;
    const bool more = (it < it0 + 31);
    // ---- issue next-tile staging first (overlaps with compute below) ----
    if (more) {
      const int kv0n = (it + 1) * 64;
      const unsigned short* vs = Vb + kv0n + ch * 8;
#pragma unroll
      for (int j = 0; j < 4; ++j)
        vreg[j] = *(const uint4*)(vs + (size_t)(dbase + j * 32) * NP);
#pragma unroll
      for (int r = 0; r < 4; ++r) {
        const int ci = wid * 256 + r * 64 + lane;
        const int kv = ci >> 4, cc = ci & 15;
        gload_lds16(Kb + (size_t)(kv0n + kv) * IC + 8 * (cc ^ (kv & 15)),
                    (char*)&Klds[cur ^ 1][0] + wid * 4096 + r * 1024);
      }
    }
    // ---- S^T[k][q] = K * Q^T (log2e pre-scaled), 4-way split chains ----
    f16v st0a, st0b, st1a, st1b;
#pragma unroll
    for (int i = 0; i < 16; ++i) { st0a[i] = 0.f; st0b[i] = 0.f; st1a[i] = 0.f; st1b[i] = 0.f; }
    const int kva = lane & 31;
    __builtin_amdgcn_s_setprio(1);
#pragma unroll
    for (int s = 0; s < 8; s += 2) {
      const int cc0 = hl + 2 * s;
      const s8v ka0 = *(const s8v*)&Klds[cur][kva * 128 + 8 * (cc0 ^ (kva & 15))];
      const s8v kb0 = *(const s8v*)&Klds[cur][(kva + 32) * 128 + 8 * (cc0 ^ (kva & 15))];
      const s8v ka1 = *(const s8v*)&Klds[cur][kva * 128 + 8 * ((cc0 + 2) ^ (kva & 15))];
      const s8v kb1 = *(const s8v*)&Klds[cur][(kva + 32) * 128 + 8 * ((cc0 + 2) ^ (kva & 15))];
      st0a = MFMA32(ka0, qf[s], st0a);
      st1a = MFMA32(kb0, qf[s], st1a);
      st0b = MFMA32(ka1, qf[s + 1], st0b);
      st1b = MFMA32(kb1, qf[s + 1], st1b);
    }
    __builtin_amdgcn_s_setprio(0);
    f16v st0 = st0a + st0b;
    f16v st1 = st1a + st1b;
    // ---- online softmax (exp2 domain, defer-rescale THR=8, tree reduces) ----
    float tm[16];
#pragma unroll
    for (int i = 0; i < 16; ++i) tm[i] = fmaxf(st0[i], st1[i]);
#pragma unroll
    for (int w = 8; w >= 1; w >>= 1)
#pragma unroll
      for (int i = 0; i < 16; ++i) if (i < w) tm[i] = fmaxf(tm[i], tm[i + w]);
    float pmax = fmaxf(tm[0], __shfl_xor(tm[0], 32));
    if (__any(pmax > m + 8.f)) {
      const float mn = fmaxf(m, pmax);
      const float sc = __builtin_amdgcn_exp2f(m - mn);
      m = mn;
      lsum *= sc;
#pragma unroll
      for (int dt = 0; dt < 4; ++dt)
#pragma unroll
        for (int i = 0; i < 16; ++i) oa[dt][i] *= sc;
    }
#pragma unroll
    for (int i = 0; i < 16; ++i) st0[i] = __builtin_amdgcn_exp2f(st0[i] - m);
#pragma unroll
    for (int i = 0; i < 16; ++i) st1[i] = __builtin_amdgcn_exp2f(st1[i] - m);
    float ts[16];
#pragma unroll
    for (int i = 0; i < 16; ++i) ts[i] = st0[i] + st1[i];
#pragma unroll
    for (int w = 8; w >= 1; w >>= 1)
#pragma unroll
      for (int i = 0; i < 16; ++i) if (i < w) ts[i] += ts[i + w];
    lsum += ts[0] + __shfl_xor(ts[0], 32);
    s8v pf0, pf1, pf2, pf3;
#pragma unroll
    for (int i = 0; i < 8; ++i) {
      pf0[i] = (short)f2bf_h(st0[i]);
      pf1[i] = (short)f2bf_h(st0[8 + i]);
      pf2[i] = (short)f2bf_h(st1[i]);
      pf3[i] = (short)f2bf_h(st1[8 + i]);
    }
    // ---- write prefetched V into the other buffer (permuted + chunk-XOR) ----
    if (more) {
#pragma unroll
      for (int j = 0; j < 4; ++j) {
        const int d = dbase + j * 32;
        const int jd = (d >> 3) & 7;
        *(uint2*)&Vlds[cur ^ 1][d * 72 + 8 * (c1 ^ jd) + w1] = make_uint2(vreg[j].x, vreg[j].y);
        *(uint2*)&Vlds[cur ^ 1][d * 72 + 8 * ((c1 + 1) ^ jd) + w1] = make_uint2(vreg[j].z, vreg[j].w);
      }
    }
    // ---- O^T[d][q] += V^T[d][k] * P^T[k][q]; one b128 per A-fragment ----
    __builtin_amdgcn_s_setprio(1);
#pragma unroll
    for (int ks = 0; ks < 4; ++ks) {
      const s8v pcur = (ks == 0) ? pf0 : ((ks == 1) ? pf1 : ((ks == 2) ? pf2 : pf3));
#pragma unroll
      for (int dt = 0; dt < 4; ++dt) {
        const int d = dt * 32 + (lane & 31);
        const int jd = (4 * dt + ((lane & 31) >> 3)) & 7;
        const s8v vf = *(const s8v*)&Vlds[cur][d * 72 + 8 * ((2 * ks + hl) ^ jd)];
        oa[dt] = MFMA32(vf, pcur, oa[dt]);
      }
    }
    __builtin_amdgcn_s_setprio(0);
    // one barrier per iter: drains K-DMA + V ds_writes, closes reads of cur
    __syncthreads();
  }
  // epilogue: normalized partial O + stats
  const float inv = 1.0f / lsum;
  unsigned short* Op = Opart + (size_t)half * NB * NP * IC + ((size_t)b * NP + q) * IC;
#pragma unroll
  for (int dt = 0; dt < 4; ++dt) {
#pragma unroll
    for (int grp = 0; grp < 4; ++grp) {
      const int d0 = dt * 32 + 8 * grp + 4 * hl;
      ushort4 u;
      u.x = f2bf_h(oa[dt][grp * 4 + 0] * inv);
      u.y = f2bf_h(oa[dt][grp * 4 + 1] * inv);
      u.z = f2bf_h(oa[dt][grp * 4 + 2] * inv);
      u.w = f2bf_h(oa[dt][grp * 4 + 3] * inv);
      *(ushort4*)(Op + d0) = u;
    }
  }
  if (hl == 0)
    stats[(size_t)half * NB * NP + (size_t)b * NP + q] = make_float2(m, lsum);
}

// ---------------------------------------------------------------------------
// Kernel 3: merge partial O halves ONCE, then both output-channel halves'
// GEMM + residual. Grid 512 (8 batches x 64 p-tiles). Weights bf16.
// ---------------------------------------------------------------------------
__global__ __launch_bounds__(256) void k_out(const unsigned short* __restrict__ Opart,
    const float2* __restrict__ stats,
    const unsigned short* __restrict__ WwB, const float* __restrict__ Wb,
    const float* __restrict__ x, float* __restrict__ out) {
  __shared__ unsigned short Y[64 * 128];  // [p][i], 16B-chunk swizzle by (p&15)
  const int t = threadIdx.x, lane = t & 63, wid = t >> 6;
  const int b = blockIdx.x & 7;           // XCD-aligned batch
  const int p0 = (blockIdx.x >> 3) * 64;
  const int hl = lane >> 5;
  // ---- merge-stage Y from the two partial halves (once) ----
  {
    const int p = t >> 2;
    const int quarter = t & 3;
    const int ihb = quarter * 32;
    const int gq = p0 + p;
    const float2 s0 = stats[(size_t)b * NP + gq];
    const float2 s1 = stats[(size_t)NB * NP + (size_t)b * NP + gq];
    const float mm = fmaxf(s0.x, s1.x);
    const float w0 = s0.y * exp2f(s0.x - mm);
    const float w1 = s1.y * exp2f(s1.x - mm);
    const float rinv = 1.0f / (w0 + w1);
    const float a0 = w0 * rinv, a1 = w1 * rinv;
    const unsigned short* P0 = Opart + ((size_t)b * NP + gq) * IC + ihb;
    const unsigned short* P1 = Opart + (size_t)NB * NP * IC + ((size_t)b * NP + gq) * IC + ihb;
#pragma unroll
    for (int c8 = 0; c8 < 4; ++c8) {
      const s8v v0 = *(const s8v*)(P0 + c8 * 8);
      const s8v v1 = *(const s8v*)(P1 + c8 * 8);
      alignas(16) unsigned short o[8];
#pragma unroll
      for (int j = 0; j < 8; ++j)
        o[j] = f2bf_h(a0 * bf2f(v0[j]) + a1 * bf2f(v1[j]));
      const int cc = quarter * 4 + c8;
      *(uint4*)&Y[p * 128 + 8 * (cc ^ (p & 15))] = *(const uint4*)o;
    }
  }
  __syncthreads();
  for (int mt = 0; mt < 2; ++mt) {
    const int orow = mt * 128 + wid * 32 + (lane & 31);
    s8v wf[8];
#pragma unroll
    for (int s = 0; s < 8; ++s)
      wf[s] = *(const s8v*)&WwB[(size_t)orow * IC + hl * 8 + 16 * s];
    float br[16];
#pragma unroll
    for (int r = 0; r < 16; ++r)
      br[r] = Wb[mt * 128 + wid * 32 + (r & 3) + 8 * (r >> 2) + 4 * hl];
#pragma unroll
    for (int nt = 0; nt < 2; ++nt) {
      const int p = (lane & 31) + nt * 32;
      f16v acc;
#pragma unroll
      for (int i = 0; i < 16; ++i) acc[i] = 0.f;
#pragma unroll
      for (int s = 0; s < 8; ++s) {
        const int cc0 = hl + 2 * s;
        const s8v yf = *(const s8v*)&Y[p * 128 + 8 * (cc0 ^ (p & 15))];
        acc = MFMA32(wf[s], yf, acc);
      }
      const size_t pidx = (size_t)b * CIN * NP + (size_t)(p0 + p);
#pragma unroll
      for (int r = 0; r < 16; ++r) {
        const int row = mt * 128 + wid * 32 + (r & 3) + 8 * (r >> 2) + 4 * hl;
        const size_t idx = pidx + (size_t)row * NP;
        out[idx] = acc[r] + br[r] + x[idx];
      }
    }
  }
}

// ---------------------------------------------------------------------------
extern "C" void kernel_launch(void* const* d_in, const int* in_sizes, int n_in,
                              void* d_out, int out_size, void* d_ws, size_t ws_size,
                              hipStream_t stream) {
  const float* x   = (const float*)d_in[0];
  const float* gw  = (const float*)d_in[1];
  const float* gb  = (const float*)d_in[2];
  const float* thw = (const float*)d_in[3];
  const float* thb = (const float*)d_in[4];
  const float* phw = (const float*)d_in[5];
  const float* phb = (const float*)d_in[6];
  const float* Ww  = (const float*)d_in[7];
  const float* Wb  = (const float*)d_in[8];
  float* out = (float*)d_out;

  // ws layout (ushorts): Opart(2 halves) 8.39M | Q 4.19M | K 4.19M | Vt 4.19M
  //                      | stats (262144) | wB (4x32768)
  unsigned short* ws  = (unsigned short*)d_ws;
  unsigned short* Opart = ws;
  unsigned short* Qg  = ws + 8388608;
  unsigned short* Kg  = Qg + 4194304;
  unsigned short* Vtg = Kg + 4194304;
  float2* stats = (float2*)(Vtg + 4194304);
  unsigned short* wB = Vtg + 4194304 + 262144;

  k_wprep<<<dim3(128), dim3(256), 0, stream>>>(thw, phw, gw, Ww, wB);
  k_conv3<<<dim3(512), dim3(256), 0, stream>>>(x, wB, thb, phb, gb,
                                               Qg, Kg, Vtg);
  k_attn<<<dim3(512), dim3(256), 0, stream>>>(Qg, Kg, Vtg, Opart, stats);
  k_out<<<dim3(512), dim3(256), 0, stream>>>(Opart, stats, wB + 98304, Wb, x, out);
}